// Round 1
// baseline (155.213 us; speedup 1.0000x reference)
//
#include <hip/hip_runtime.h>

// LocalConnectivity: out[i][j] = sum_{1<=|dx|+|dy|<=5} w_{|dx|+|dy|} * s[(i+dx)&4095][(j+dy)&4095]
// w_d = exp(-d/2) = r^d  =>  separable: w_{|dx|+|dy|} = r^{|dx|} * r^{|dy|}
//
// out[i][j] = sum_{dx=-5..5} r^{|dx|} * H_{5-|dx|}[i+dx][j] - s[i][j]
// H_k[t][j] = sum_{|dy|<=k} r^{|dy|} s[t][j+dy], built incrementally (5 add + 5 fma).
//
// One thread = 4 columns, streams 44 input rows (34 output rows + 10 halo) with a
// ring of 11 register accumulators (scatter form). No LDS, no syncthreads.

#define GH 4096
#define GW 4096
#define GMASK 4095
#define RCHUNK 34   // output rows per block
#define NITER 4     // 4 * 11 = 44 = RCHUNK + 10 input rows processed

__global__ __launch_bounds__(128)
void diamond_stencil(const float* __restrict__ s, const float* __restrict__ w,
                     float* __restrict__ out)
{
    const int tid   = threadIdx.x;
    const int strip = blockIdx.x;          // 0..7  -> 512-wide column strip
    const int chunk = blockIdx.y;          // 0..120 -> 34-row chunk
    const int j0 = strip * 512 + tid * 4;  // first of this thread's 4 columns
    const int t0 = chunk * RCHUNK;         // first output row of this chunk

    // wrapped column offsets (elements); all float4 bases stay 16B-aligned
    const int cm5 = (j0 - 5) & GMASK;
    const int cm4 = (j0 - 4) & GMASK;
    const int cp4 = (j0 + 4) & GMASK;
    const int cp8 = (j0 + 8) & GMASK;

    float wv[6];
    wv[0] = 1.0f;
#pragma unroll
    for (int d = 1; d <= 5; ++d) wv[d] = w[d - 1];   // exp(-d/2)

    // ring of 11 accumulators x 4 columns; slot(o) = (o - t0) mod 11
    float acc[11][4];
#pragma unroll
    for (int i = 0; i < 11; ++i)
#pragma unroll
        for (int c = 0; c < 4; ++c) acc[i][c] = 0.0f;

#pragma unroll 1
    for (int it = 0; it < NITER; ++it) {
        const int tbase = t0 - 5 + it * 11;
#pragma unroll
        for (int ph = 0; ph < 11; ++ph) {
            const int t = tbase + ph;                       // input row
            const int rbase = (t & GMASK) << 12;            // *4096 cols
            const float* srow = s + rbase;

            // load columns j0-5 .. j0+8 (14 floats) of row t
            float v[14];
            v[0] = srow[cm5];
            const float4 A = *(const float4*)(srow + cm4);
            const float4 B = *(const float4*)(srow + j0);
            const float4 C = *(const float4*)(srow + cp4);
            v[1] = A.x; v[2]  = A.y; v[3]  = A.z; v[4]  = A.w;
            v[5] = B.x; v[6]  = B.y; v[7]  = B.z; v[8]  = B.w;
            v[9] = C.x; v[10] = C.y; v[11] = C.z; v[12] = C.w;
            v[13] = srow[cp8];

#pragma unroll
            for (int c = 0; c < 4; ++c) {
                const float ctr = v[5 + c];
                float Hs[6];
                Hs[0] = ctr;
#pragma unroll
                for (int k = 1; k <= 5; ++k)
                    Hs[k] = Hs[k - 1] + wv[k] * (v[5 + c - k] + v[5 + c + k]);

                // scatter: row t contributes to output rows o = t+d, d = -5..5
                // slot(o) = (o - t0) mod 11 = (ph + d + 6) mod 11   (static)
                acc[(ph + 6) % 11][c] += Hs[5] - ctr;       // d = 0 (center removed)
#pragma unroll
                for (int d = 1; d <= 5; ++d) {
                    const float contrib = wv[d] * Hs[5 - d];
                    acc[(ph + d + 6) % 11][c] += contrib;   // d = +d
                    acc[(ph - d + 6) % 11][c] += contrib;   // d = -d
                }
            }

            // output row o = t - 5 is now complete (last contributor is t)
            {
                const int o  = tbase + ph - 5;
                const int sl = (ph + 1) % 11;               // = (o - t0) mod 11
                if (o >= t0 && o < GH) {
                    float4 r;
                    r.x = acc[sl][0]; r.y = acc[sl][1];
                    r.z = acc[sl][2]; r.w = acc[sl][3];
                    *(float4*)(out + ((size_t)o << 12) + j0) = r;
                }
                // always clear: slot is recycled for row o+11 starting next input row
                acc[sl][0] = 0.0f; acc[sl][1] = 0.0f;
                acc[sl][2] = 0.0f; acc[sl][3] = 0.0f;
            }
        }
    }
}

extern "C" void kernel_launch(void* const* d_in, const int* in_sizes, int n_in,
                              void* d_out, int out_size, void* d_ws, size_t ws_size,
                              hipStream_t stream)
{
    const float* s = (const float*)d_in[0];   // grid_spikes [4096*4096] f32
    const float* w = (const float*)d_in[1];   // distance_weights [5] f32
    float* out = (float*)d_out;               // [4096*4096] f32

    dim3 grid(8, (GH + RCHUNK - 1) / RCHUNK);  // 8 strips x 121 chunks = 968 blocks
    dim3 block(128);
    diamond_stencil<<<grid, block, 0, stream>>>(s, w, out);
}